// Round 4
// baseline (1103.619 us; speedup 1.0000x reference)
//
#include <hip/hip_runtime.h>
#include <hip/hip_bf16.h>

// GCN 2-layer on MI355X.
// Pipeline (agg-first form, valid since aggregation is linear):
//   A = agg(x); B = relu(A@W1+b1); A = agg(B); B = relu(A@W2+b2); out = B@Wl+bl
// CSR built once per launch (deg -> scan -> scatter), reused by both aggs.
//
// R2 fix (unvalidated — R3 GPU acquisition timed out): edge_index is staged
// as INT32 by the harness (JAX x64 disabled downcasts jnp.int64 -> int32;
// harness doc: "integer -> const int*"). R1's const long long* cast read
// past the buffer end -> core dump.

#define NB_T 256

__global__ void k_init_deg(int* deg, int n) {
    int i = blockIdx.x * NB_T + threadIdx.x;
    if (i < n) deg[i] = 1;   // self-loop
}

__global__ void k_count(const int* __restrict__ dst, int E, int* deg) {
    int e = blockIdx.x * NB_T + threadIdx.x;
    if (e < E) atomicAdd(&deg[dst[e]], 1);
}

__global__ void k_dinv(const int* __restrict__ deg, float* __restrict__ dinv, int n) {
    int i = blockIdx.x * NB_T + threadIdx.x;
    if (i < n) dinv[i] = rsqrtf((float)deg[i]);
}

// ---- 3-phase exclusive scan of deg[0..n) -> rowStart[0..n], cursor copy ----
__global__ void k_scan_part(const int* __restrict__ deg, int n, int chunk, int* blockSums) {
    __shared__ int sh[NB_T];
    int b = blockIdx.x, t = threadIdx.x;
    int lo = b * chunk, hi = min(lo + chunk, n);
    int base = lo + t * 2;
    int s = 0;
    if (base     < hi) s += deg[base];
    if (base + 1 < hi) s += deg[base + 1];
    sh[t] = s; __syncthreads();
    for (int off = 128; off > 0; off >>= 1) {
        if (t < off) sh[t] += sh[t + off];
        __syncthreads();
    }
    if (t == 0) blockSums[b] = sh[0];
}

__global__ void k_scan_mid(const int* __restrict__ blockSums, int* blockOff, int* rowStart, int n) {
    __shared__ int sh[NB_T];
    int t = threadIdx.x;
    int v = blockSums[t];
    sh[t] = v; __syncthreads();
    for (int off = 1; off < NB_T; off <<= 1) {
        int u = (t >= off) ? sh[t - off] : 0;
        __syncthreads();
        sh[t] += u;
        __syncthreads();
    }
    blockOff[t] = sh[t] - v;            // exclusive
    if (t == NB_T - 1) rowStart[n] = sh[t];  // total = E + n
}

__global__ void k_scan_final(const int* __restrict__ deg, int n, int chunk,
                             const int* __restrict__ blockOff, int* rowStart, int* cursor) {
    __shared__ int sh[NB_T];
    int b = blockIdx.x, t = threadIdx.x;
    int lo = b * chunk, hi = min(lo + chunk, n);
    int base = lo + t * 2;
    int d0 = 0, d1 = 0;
    if (base     < hi) d0 = deg[base];
    if (base + 1 < hi) d1 = deg[base + 1];
    int ts = d0 + d1;
    sh[t] = ts; __syncthreads();
    for (int off = 1; off < NB_T; off <<= 1) {
        int u = (t >= off) ? sh[t - off] : 0;
        __syncthreads();
        sh[t] += u;
        __syncthreads();
    }
    int pref = blockOff[b] + sh[t] - ts;  // exclusive prefix for this thread's 2 elems
    if (base < hi) { rowStart[base] = pref; cursor[base] = pref; pref += d0; }
    if (base + 1 < hi) { rowStart[base + 1] = pref; cursor[base + 1] = pref; }
}

__global__ void k_scatter(const int* __restrict__ src, const int* __restrict__ dst,
                          int E, int n, int* cursor, int* __restrict__ sortedSrc) {
    int e = blockIdx.x * NB_T + threadIdx.x;
    int tot = E + n;
    if (e >= tot) return;
    int s, d;
    if (e < E) { s = src[e]; d = dst[e]; }
    else       { s = d = e - E; }              // self-loop
    int pos = atomicAdd(&cursor[d], 1);
    sortedSrc[pos] = s;
}

// ---- aggregation: G[d] = dinv[d] * sum_{e in row d} dinv[src_e] * F[src_e] ----
// one 64-lane wave per node; lane holds float2 (feats 2*lane, 2*lane+1)
// unrolled x4: 4 index loads, then 4 dinv + 4 row-gathers in flight together
__global__ __launch_bounds__(256) void k_agg(const float* __restrict__ F, float* __restrict__ G,
                                             const int* __restrict__ rowStart,
                                             const int* __restrict__ sortedSrc,
                                             const float* __restrict__ dinv, int n) {
    int wave = threadIdx.x >> 6;
    int lane = threadIdx.x & 63;
    int node = blockIdx.x * 4 + wave;
    if (node >= n) return;
    int r0 = rowStart[node], r1 = rowStart[node + 1];
    int f = lane * 2;
    float ax = 0.f, ay = 0.f;
    int e = r0;
    for (; e + 4 <= r1; e += 4) {
        int s0 = sortedSrc[e];
        int s1 = sortedSrc[e + 1];
        int s2 = sortedSrc[e + 2];
        int s3 = sortedSrc[e + 3];
        float w0 = dinv[s0], w1 = dinv[s1], w2 = dinv[s2], w3 = dinv[s3];
        float2 v0 = *(const float2*)(F + (size_t)s0 * 128 + f);
        float2 v1 = *(const float2*)(F + (size_t)s1 * 128 + f);
        float2 v2 = *(const float2*)(F + (size_t)s2 * 128 + f);
        float2 v3 = *(const float2*)(F + (size_t)s3 * 128 + f);
        ax += w0 * v0.x + w1 * v1.x + w2 * v2.x + w3 * v3.x;
        ay += w0 * v0.y + w1 * v1.y + w2 * v2.y + w3 * v3.y;
    }
    for (; e < r1; e++) {
        int s0 = sortedSrc[e];
        float w0 = dinv[s0];
        float2 v0 = *(const float2*)(F + (size_t)s0 * 128 + f);
        ax += w0 * v0.x; ay += w0 * v0.y;
    }
    float wd = dinv[node];
    float2 o; o.x = ax * wd; o.y = ay * wd;
    *(float2*)(G + (size_t)node * 128 + f) = o;
}

// ---- f32 GEMM: G[n][c] = relu( sum_k F[n][k]*W[k][c] + bias[c] ) ----
// tile 64 rows/block; only x-tile (64x132 padded, 33KB) in LDS -> 4 blocks/CU.
// W (64KB) read from global: identical across blocks -> L1/L2 broadcast.
__device__ __forceinline__ float f4c(const float4 v, int k) {
    return k == 0 ? v.x : k == 1 ? v.y : k == 2 ? v.z : v.w;
}

__global__ __launch_bounds__(256, 4) void k_gemm(const float* __restrict__ F,
                                                 const float* __restrict__ W,
                                                 const float* __restrict__ bias,
                                                 float* __restrict__ G, int n) {
    __shared__ float x_lds[64 * 132];
    int t = threadIdx.x;
    int tileBase = blockIdx.x * 64;

    // stage x tile, padded stride 132 to break bank alias on reads
    #pragma unroll
    for (int i = 0; i < 8; i++) {
        int row = i * 8 + (t >> 5);
        int k4  = t & 31;
        int grow = tileBase + row;
        float4 v = make_float4(0.f, 0.f, 0.f, 0.f);
        if (grow < n) v = *(const float4*)&F[(size_t)grow * 128 + k4 * 4];
        *(float4*)&x_lds[row * 132 + k4 * 4] = v;
    }
    __syncthreads();

    int r0 = (t >> 4) * 4;          // 4 rows per thread
    int c0 = (t & 15) * 4;          // cols {c0..c0+3} U {c0+64..c0+67}
    float acc[4][8];
    #pragma unroll
    for (int i = 0; i < 4; i++)
        #pragma unroll
        for (int j = 0; j < 8; j++) acc[i][j] = 0.f;

    for (int k0 = 0; k0 < 128; k0 += 4) {
        float4 xv[4];
        #pragma unroll
        for (int i = 0; i < 4; i++) xv[i] = *(float4*)&x_lds[(r0 + i) * 132 + k0];
        #pragma unroll
        for (int kk = 0; kk < 4; kk++) {
            float4 w1 = *(const float4*)&W[(k0 + kk) * 128 + c0];
            float4 w2 = *(const float4*)&W[(k0 + kk) * 128 + c0 + 64];
            #pragma unroll
            for (int i = 0; i < 4; i++) {
                float xs = f4c(xv[i], kk);
                acc[i][0] += xs * w1.x; acc[i][1] += xs * w1.y;
                acc[i][2] += xs * w1.z; acc[i][3] += xs * w1.w;
                acc[i][4] += xs * w2.x; acc[i][5] += xs * w2.y;
                acc[i][6] += xs * w2.z; acc[i][7] += xs * w2.w;
            }
        }
    }

    float bv[8];
    #pragma unroll
    for (int j = 0; j < 4; j++) { bv[j] = bias[c0 + j]; bv[4 + j] = bias[c0 + 64 + j]; }
    #pragma unroll
    for (int i = 0; i < 4; i++) {
        int grow = tileBase + r0 + i;
        if (grow < n) {
            float4 o1, o2;
            o1.x = fmaxf(acc[i][0] + bv[0], 0.f); o1.y = fmaxf(acc[i][1] + bv[1], 0.f);
            o1.z = fmaxf(acc[i][2] + bv[2], 0.f); o1.w = fmaxf(acc[i][3] + bv[3], 0.f);
            o2.x = fmaxf(acc[i][4] + bv[4], 0.f); o2.y = fmaxf(acc[i][5] + bv[5], 0.f);
            o2.z = fmaxf(acc[i][6] + bv[6], 0.f); o2.w = fmaxf(acc[i][7] + bv[7], 0.f);
            *(float4*)&G[(size_t)grow * 128 + c0]      = o1;
            *(float4*)&G[(size_t)grow * 128 + c0 + 64] = o2;
        }
    }
}

// ---- final linear 128 -> 2, one wave per node, shuffle reduce ----
__global__ __launch_bounds__(256) void k_out(const float* __restrict__ F,
                                             const float* __restrict__ Wl,
                                             const float* __restrict__ bl,
                                             float* __restrict__ out, int n) {
    int wave = threadIdx.x >> 6;
    int lane = threadIdx.x & 63;
    int node = blockIdx.x * 4 + wave;
    if (node >= n) return;
    int f = lane * 2;
    float2 v = *(const float2*)(F + (size_t)node * 128 + f);
    float w00 = Wl[f * 2 + 0], w01 = Wl[f * 2 + 1];
    float w10 = Wl[f * 2 + 2], w11 = Wl[f * 2 + 3];
    float a0 = v.x * w00 + v.y * w10;
    float a1 = v.x * w01 + v.y * w11;
    for (int m = 32; m >= 1; m >>= 1) {
        a0 += __shfl_xor(a0, m, 64);
        a1 += __shfl_xor(a1, m, 64);
    }
    if (lane == 0) {
        out[(size_t)node * 2 + 0] = a0 + bl[0];
        out[(size_t)node * 2 + 1] = a1 + bl[1];
    }
}

extern "C" void kernel_launch(void* const* d_in, const int* in_sizes, int n_in,
                              void* d_out, int out_size, void* d_ws, size_t ws_size,
                              hipStream_t stream) {
    const float* x   = (const float*)d_in[0];
    const int*   ei  = (const int*)d_in[1];     // int32! (JAX x64 off)
    const float* W1  = (const float*)d_in[2];
    const float* b1  = (const float*)d_in[3];
    const float* W2  = (const float*)d_in[4];
    const float* b2  = (const float*)d_in[5];
    const float* Wl  = (const float*)d_in[6];
    const float* bl  = (const float*)d_in[7];
    float*       out = (float*)d_out;

    const int N = in_sizes[0] / 128;
    const int E = in_sizes[1] / 2;
    const int* src = ei;
    const int* dst = ei + E;

    // workspace carve-up (~117 MB total)
    char* p = (char*)d_ws;
    auto alloc = [&](size_t bytes) -> char* {
        char* r = p;
        p += (bytes + 511) & ~(size_t)511;
        return r;
    };
    int*   deg       = (int*)alloc((size_t)N * 4);
    float* dinv      = (float*)alloc((size_t)N * 4);
    int*   rowStart  = (int*)alloc((size_t)(N + 1) * 4);
    int*   cursor    = (int*)alloc((size_t)N * 4);
    int*   blockSums = (int*)alloc(256 * 4);
    int*   blockOff  = (int*)alloc(256 * 4);
    int*   sortedSrc = (int*)alloc((size_t)(E + N) * 4);
    float* A         = (float*)alloc((size_t)N * 128 * 4);
    float* B         = (float*)alloc((size_t)N * 128 * 4);

    int nb = (N + NB_T - 1) / NB_T;
    int chunk = (N + 255) / 256;

    k_init_deg<<<nb, NB_T, 0, stream>>>(deg, N);
    k_count<<<(E + NB_T - 1) / NB_T, NB_T, 0, stream>>>(dst, E, deg);
    k_dinv<<<nb, NB_T, 0, stream>>>(deg, dinv, N);
    k_scan_part<<<256, NB_T, 0, stream>>>(deg, N, chunk, blockSums);
    k_scan_mid<<<1, NB_T, 0, stream>>>(blockSums, blockOff, rowStart, N);
    k_scan_final<<<256, NB_T, 0, stream>>>(deg, N, chunk, blockOff, rowStart, cursor);
    k_scatter<<<(E + N + NB_T - 1) / NB_T, NB_T, 0, stream>>>(src, dst, E, N, cursor, sortedSrc);

    // conv1: A = agg(x); B = relu(A@W1 + b1)
    k_agg<<<(N + 3) / 4, NB_T, 0, stream>>>(x, A, rowStart, sortedSrc, dinv, N);
    k_gemm<<<(N + 63) / 64, NB_T, 0, stream>>>(A, W1, b1, B, N);
    // conv2: A = agg(B); B = relu(A@W2 + b2)
    k_agg<<<(N + 3) / 4, NB_T, 0, stream>>>(B, A, rowStart, sortedSrc, dinv, N);
    k_gemm<<<(N + 63) / 64, NB_T, 0, stream>>>(A, W2, b2, B, N);
    // final linear
    k_out<<<(N + 3) / 4, NB_T, 0, stream>>>(B, Wl, bl, out, N);
}

// Round 6
// 824.105 us; speedup vs baseline: 1.3392x; 1.3392x over previous
//
#include <hip/hip_runtime.h>
#include <hip/hip_bf16.h>

// GCN 2-layer on MI355X.
// Pipeline (agg-first form, valid since aggregation is linear):
//   A = agg(x); B = relu(A@W1+b1); A = agg(B); B = relu(A@W2+b2); out = B@Wl+bl
//
// R4 counters: k_scatter 290us, WRITE_SIZE 197MB for a 13MB payload (16x
// line-eviction amplification from random 4B writes across 8 non-coherent
// L2s). k_count same pattern. CSR build ~390us of 1103us total.
// R5 (resubmitted R6 — acquisition timeout): two-level counting sort.
//   Bucket = dst>>9 (512 nodes, 256 buckets).
//   A0: LDS histogram -> 256 global atomics/block.
//   scan: 256 totals, 1 block. Also rowStart[N]=E+N.
//   A1: reserve contiguous per-(block,bucket) runs, write packed edge
//       ((dst&511)<<17 | src) -> coalesced full-line writes (~13MB).
//   B: per-bucket block: LDS count[512]+scan -> rowStart/dinv coalesced,
//      scatter sortedSrc within 68KB L2-resident region.
// binned[] aliases A (dead by first k_agg) -> workspace unchanged ~116MB.

#define NB_T   256
#define NBUCK  256
#define BSHIFT 9
#define EPB    4096   // edges per block in binning passes

__global__ void k_zero_buckets(int* bucketTotal) {
    bucketTotal[threadIdx.x] = 0;
}

// ---- Pass A0: count edges per bucket (LDS histogram -> global merge) ----
__global__ __launch_bounds__(NB_T) void k_binCount(const int* __restrict__ src,
                                                   const int* __restrict__ dst,
                                                   int E, int n, int* bucketTotal) {
    __shared__ int hist[NBUCK];
    int t = threadIdx.x;
    hist[t] = 0;
    __syncthreads();
    int lo = blockIdx.x * EPB;
    int hi = min(lo + EPB, E + n);
    for (int e = lo + t; e < hi; e += NB_T) {
        int d = (e < E) ? dst[e] : (e - E);   // tail = self-loops
        atomicAdd(&hist[d >> BSHIFT], 1);
    }
    __syncthreads();
    int h = hist[t];
    if (h) atomicAdd(&bucketTotal[t], h);
}

// ---- scan 256 bucket totals -> bucketBase[257], cursor copy ----
__global__ void k_bscan(const int* __restrict__ bucketTotal, int* bucketBase,
                        int* bucketCursor, int* rowStart, int E, int n) {
    __shared__ int sh[NBUCK];
    int t = threadIdx.x;
    int v = bucketTotal[t];
    sh[t] = v; __syncthreads();
    for (int off = 1; off < NBUCK; off <<= 1) {
        int u = (t >= off) ? sh[t - off] : 0;
        __syncthreads();
        sh[t] += u;
        __syncthreads();
    }
    int ex = sh[t] - v;          // exclusive
    bucketBase[t] = ex;
    bucketCursor[t] = ex;
    if (t == NBUCK - 1) { bucketBase[NBUCK] = sh[t]; rowStart[n] = E + n; }
}

// ---- Pass A1: scatter packed edges into per-(block,bucket) contiguous runs ----
__global__ __launch_bounds__(NB_T) void k_binScatter(const int* __restrict__ src,
                                                     const int* __restrict__ dst,
                                                     int E, int n, int* bucketCursor,
                                                     unsigned int* __restrict__ binned) {
    __shared__ int hist[NBUCK];
    __shared__ int base[NBUCK];
    int t = threadIdx.x;
    hist[t] = 0;
    __syncthreads();
    int lo = blockIdx.x * EPB;
    int hi = min(lo + EPB, E + n);
    for (int e = lo + t; e < hi; e += NB_T) {
        int d = (e < E) ? dst[e] : (e - E);
        atomicAdd(&hist[d >> BSHIFT], 1);
    }
    __syncthreads();
    int h = hist[t];                 // thread t owns slot t only: no race
    if (h) base[t] = atomicAdd(&bucketCursor[t], h);
    hist[t] = 0;                     // reuse as per-block run cursor
    __syncthreads();
    for (int e = lo + t; e < hi; e += NB_T) {
        int s, d;
        if (e < E) { s = src[e]; d = dst[e]; }
        else       { s = d = e - E; }
        int b = d >> BSHIFT;
        int pos = base[b] + atomicAdd(&hist[b], 1);
        binned[pos] = ((unsigned)(d & 511) << 17) | (unsigned)s;  // N < 2^17
    }
}

// ---- Pass B: per-bucket CSR finalize (count, scan, rowStart/dinv, scatter) ----
__global__ __launch_bounds__(NB_T) void k_csr(const unsigned int* __restrict__ binned,
                                              const int* __restrict__ bucketBase,
                                              int* __restrict__ rowStart,
                                              float* __restrict__ dinv,
                                              int* __restrict__ sortedSrc, int n) {
    __shared__ int cnt[512];
    __shared__ int start[512];
    __shared__ int sh[NB_T];
    int b = blockIdx.x, t = threadIdx.x;
    int ebase = bucketBase[b], eend = bucketBase[b + 1];
    cnt[t] = 0; cnt[t + 256] = 0;
    __syncthreads();
    for (int e = ebase + t; e < eend; e += NB_T)
        atomicAdd(&cnt[binned[e] >> 17], 1);
    __syncthreads();
    // exclusive scan of cnt[0..512), 2 elems/thread
    int c0 = cnt[t * 2], c1 = cnt[t * 2 + 1];
    int ts = c0 + c1;
    sh[t] = ts; __syncthreads();
    for (int off = 1; off < NB_T; off <<= 1) {
        int u = (t >= off) ? sh[t - off] : 0;
        __syncthreads();
        sh[t] += u;
        __syncthreads();
    }
    int pref = sh[t] - ts;
    start[t * 2]     = pref;
    start[t * 2 + 1] = pref + c0;
    __syncthreads();
    // rowStart + dinv (deg incl. self-loop, always > 0)
    int node0 = b << BSHIFT;
    for (int i = t; i < 512; i += NB_T) {
        int node = node0 + i;
        if (node < n) {
            rowStart[node] = ebase + start[i];
            dinv[node] = rsqrtf((float)cnt[i]);
        }
    }
    __syncthreads();
    cnt[t] = 0; cnt[t + 256] = 0;    // reuse as scatter cursor
    __syncthreads();
    for (int e = ebase + t; e < eend; e += NB_T) {
        unsigned p = binned[e];
        int i = p >> 17;
        int pos = ebase + start[i] + atomicAdd(&cnt[i], 1);
        sortedSrc[pos] = (int)(p & 0x1FFFF);
    }
}

// ---- aggregation: G[d] = dinv[d] * sum_{e in row d} dinv[src_e] * F[src_e] ----
__global__ __launch_bounds__(256) void k_agg(const float* __restrict__ F, float* __restrict__ G,
                                             const int* __restrict__ rowStart,
                                             const int* __restrict__ sortedSrc,
                                             const float* __restrict__ dinv, int n) {
    int wave = threadIdx.x >> 6;
    int lane = threadIdx.x & 63;
    int node = blockIdx.x * 4 + wave;
    if (node >= n) return;
    int r0 = rowStart[node], r1 = rowStart[node + 1];
    int f = lane * 2;
    float ax = 0.f, ay = 0.f;
    int e = r0;
    for (; e + 4 <= r1; e += 4) {
        int s0 = sortedSrc[e];
        int s1 = sortedSrc[e + 1];
        int s2 = sortedSrc[e + 2];
        int s3 = sortedSrc[e + 3];
        float w0 = dinv[s0], w1 = dinv[s1], w2 = dinv[s2], w3 = dinv[s3];
        float2 v0 = *(const float2*)(F + (size_t)s0 * 128 + f);
        float2 v1 = *(const float2*)(F + (size_t)s1 * 128 + f);
        float2 v2 = *(const float2*)(F + (size_t)s2 * 128 + f);
        float2 v3 = *(const float2*)(F + (size_t)s3 * 128 + f);
        ax += w0 * v0.x + w1 * v1.x + w2 * v2.x + w3 * v3.x;
        ay += w0 * v0.y + w1 * v1.y + w2 * v2.y + w3 * v3.y;
    }
    for (; e < r1; e++) {
        int s0 = sortedSrc[e];
        float w0 = dinv[s0];
        float2 v0 = *(const float2*)(F + (size_t)s0 * 128 + f);
        ax += w0 * v0.x; ay += w0 * v0.y;
    }
    float wd = dinv[node];
    float2 o; o.x = ax * wd; o.y = ay * wd;
    *(float2*)(G + (size_t)node * 128 + f) = o;
}

// ---- f32 GEMM: G[n][c] = relu( sum_k F[n][k]*W[k][c] + bias[c] ) ----
__device__ __forceinline__ float f4c(const float4 v, int k) {
    return k == 0 ? v.x : k == 1 ? v.y : k == 2 ? v.z : v.w;
}

__global__ __launch_bounds__(256, 4) void k_gemm(const float* __restrict__ F,
                                                 const float* __restrict__ W,
                                                 const float* __restrict__ bias,
                                                 float* __restrict__ G, int n) {
    __shared__ float x_lds[64 * 132];
    int t = threadIdx.x;
    int tileBase = blockIdx.x * 64;

    #pragma unroll
    for (int i = 0; i < 8; i++) {
        int row = i * 8 + (t >> 5);
        int k4  = t & 31;
        int grow = tileBase + row;
        float4 v = make_float4(0.f, 0.f, 0.f, 0.f);
        if (grow < n) v = *(const float4*)&F[(size_t)grow * 128 + k4 * 4];
        *(float4*)&x_lds[row * 132 + k4 * 4] = v;
    }
    __syncthreads();

    int r0 = (t >> 4) * 4;
    int c0 = (t & 15) * 4;
    float acc[4][8];
    #pragma unroll
    for (int i = 0; i < 4; i++)
        #pragma unroll
        for (int j = 0; j < 8; j++) acc[i][j] = 0.f;

    for (int k0 = 0; k0 < 128; k0 += 4) {
        float4 xv[4];
        #pragma unroll
        for (int i = 0; i < 4; i++) xv[i] = *(float4*)&x_lds[(r0 + i) * 132 + k0];
        #pragma unroll
        for (int kk = 0; kk < 4; kk++) {
            float4 w1 = *(const float4*)&W[(k0 + kk) * 128 + c0];
            float4 w2 = *(const float4*)&W[(k0 + kk) * 128 + c0 + 64];
            #pragma unroll
            for (int i = 0; i < 4; i++) {
                float xs = f4c(xv[i], kk);
                acc[i][0] += xs * w1.x; acc[i][1] += xs * w1.y;
                acc[i][2] += xs * w1.z; acc[i][3] += xs * w1.w;
                acc[i][4] += xs * w2.x; acc[i][5] += xs * w2.y;
                acc[i][6] += xs * w2.z; acc[i][7] += xs * w2.w;
            }
        }
    }

    float bv[8];
    #pragma unroll
    for (int j = 0; j < 4; j++) { bv[j] = bias[c0 + j]; bv[4 + j] = bias[c0 + 64 + j]; }
    #pragma unroll
    for (int i = 0; i < 4; i++) {
        int grow = tileBase + r0 + i;
        if (grow < n) {
            float4 o1, o2;
            o1.x = fmaxf(acc[i][0] + bv[0], 0.f); o1.y = fmaxf(acc[i][1] + bv[1], 0.f);
            o1.z = fmaxf(acc[i][2] + bv[2], 0.f); o1.w = fmaxf(acc[i][3] + bv[3], 0.f);
            o2.x = fmaxf(acc[i][4] + bv[4], 0.f); o2.y = fmaxf(acc[i][5] + bv[5], 0.f);
            o2.z = fmaxf(acc[i][6] + bv[6], 0.f); o2.w = fmaxf(acc[i][7] + bv[7], 0.f);
            *(float4*)&G[(size_t)grow * 128 + c0]      = o1;
            *(float4*)&G[(size_t)grow * 128 + c0 + 64] = o2;
        }
    }
}

// ---- final linear 128 -> 2, one wave per node, shuffle reduce ----
__global__ __launch_bounds__(256) void k_out(const float* __restrict__ F,
                                             const float* __restrict__ Wl,
                                             const float* __restrict__ bl,
                                             float* __restrict__ out, int n) {
    int wave = threadIdx.x >> 6;
    int lane = threadIdx.x & 63;
    int node = blockIdx.x * 4 + wave;
    if (node >= n) return;
    int f = lane * 2;
    float2 v = *(const float2*)(F + (size_t)node * 128 + f);
    float w00 = Wl[f * 2 + 0], w01 = Wl[f * 2 + 1];
    float w10 = Wl[f * 2 + 2], w11 = Wl[f * 2 + 3];
    float a0 = v.x * w00 + v.y * w10;
    float a1 = v.x * w01 + v.y * w11;
    for (int m = 32; m >= 1; m >>= 1) {
        a0 += __shfl_xor(a0, m, 64);
        a1 += __shfl_xor(a1, m, 64);
    }
    if (lane == 0) {
        out[(size_t)node * 2 + 0] = a0 + bl[0];
        out[(size_t)node * 2 + 1] = a1 + bl[1];
    }
}

extern "C" void kernel_launch(void* const* d_in, const int* in_sizes, int n_in,
                              void* d_out, int out_size, void* d_ws, size_t ws_size,
                              hipStream_t stream) {
    const float* x   = (const float*)d_in[0];
    const int*   ei  = (const int*)d_in[1];     // int32 (JAX x64 off)
    const float* W1  = (const float*)d_in[2];
    const float* b1  = (const float*)d_in[3];
    const float* W2  = (const float*)d_in[4];
    const float* b2  = (const float*)d_in[5];
    const float* Wl  = (const float*)d_in[6];
    const float* bl  = (const float*)d_in[7];
    float*       out = (float*)d_out;

    const int N = in_sizes[0] / 128;
    const int E = in_sizes[1] / 2;
    const int* src = ei;
    const int* dst = ei + E;

    char* p = (char*)d_ws;
    auto alloc = [&](size_t bytes) -> char* {
        char* r = p;
        p += (bytes + 511) & ~(size_t)511;
        return r;
    };
    float* dinv         = (float*)alloc((size_t)N * 4);
    int*   rowStart     = (int*)alloc((size_t)(N + 1) * 4);
    int*   bucketTotal  = (int*)alloc(NBUCK * 4);
    int*   bucketBase   = (int*)alloc((NBUCK + 1) * 4);
    int*   bucketCursor = (int*)alloc(NBUCK * 4);
    int*   sortedSrc    = (int*)alloc((size_t)(E + N) * 4);
    float* A            = (float*)alloc((size_t)N * 128 * 4);
    float* B            = (float*)alloc((size_t)N * 128 * 4);
    unsigned int* binned = (unsigned int*)A;   // dead by first k_agg

    int nbBin  = (E + N + EPB - 1) / EPB;
    int nBuckA = (N + 511) >> BSHIFT;

    k_zero_buckets<<<1, NBUCK, 0, stream>>>(bucketTotal);
    k_binCount<<<nbBin, NB_T, 0, stream>>>(src, dst, E, N, bucketTotal);
    k_bscan<<<1, NBUCK, 0, stream>>>(bucketTotal, bucketBase, bucketCursor, rowStart, E, N);
    k_binScatter<<<nbBin, NB_T, 0, stream>>>(src, dst, E, N, bucketCursor, binned);
    k_csr<<<nBuckA, NB_T, 0, stream>>>(binned, bucketBase, rowStart, dinv, sortedSrc, N);

    // conv1: A = agg(x); B = relu(A@W1 + b1)
    k_agg<<<(N + 3) / 4, NB_T, 0, stream>>>(x, A, rowStart, sortedSrc, dinv, N);
    k_gemm<<<(N + 63) / 64, NB_T, 0, stream>>>(A, W1, b1, B, N);
    // conv2: A = agg(B); B = relu(A@W2 + b2)
    k_agg<<<(N + 3) / 4, NB_T, 0, stream>>>(B, A, rowStart, sortedSrc, dinv, N);
    k_gemm<<<(N + 63) / 64, NB_T, 0, stream>>>(A, W2, b2, B, N);
    // final linear
    k_out<<<(N + 3) / 4, NB_T, 0, stream>>>(B, Wl, bl, out, N);
}

// Round 12
// 624.363 us; speedup vs baseline: 1.7676x; 1.3199x over previous
//
#include <hip/hip_runtime.h>
#include <hip/hip_bf16.h>

// GCN 2-layer on MI355X.
// Pipeline (agg-first form, valid since aggregation is linear):
//   xh = bf16(dinv.*x); A = agg(xh); Bh = bf16(dinv.*relu(A@W1+b1));
//   A = agg(Bh); B = relu(A@W2+b2); out = B@Wl+bl
//
// R6 counters: k_agg 230us x2 (56% of 824us), FETCH 800MB vs 1.69GB gather
// volume, VALUBusy 20%, hbm 47% -> bound by gather traffic on L2-miss path.
// R7 (resubmitted R8-R12 — acquisition timeouts):
//     (a) gather features in bf16 (halves gather bytes 1.69GB->845MB);
//     (b) fold dinv[src] into features (pre-scaled rows; exact reordering)
//     -> per-edge work = 1 index + 1 ushort2 gather + 2 cvt + 2 add.
// xh/Bh alias the B buffer (B only written by gemm2, after agg2 is done).

#define NB_T   256
#define NBUCK  256
#define BSHIFT 9
#define EPB    4096   // edges per block in binning passes

__device__ __forceinline__ unsigned short f2bf(float f) {
    unsigned u = __float_as_uint(f);
    u += 0x7FFF + ((u >> 16) & 1);      // round-to-nearest-even
    return (unsigned short)(u >> 16);
}
__device__ __forceinline__ float bf2f(unsigned short h) {
    return __uint_as_float((unsigned)h << 16);
}

__global__ void k_zero_buckets(int* bucketTotal) {
    bucketTotal[threadIdx.x] = 0;
}

// ---- Pass A0: count edges per bucket (LDS histogram -> global merge) ----
__global__ __launch_bounds__(NB_T) void k_binCount(const int* __restrict__ src,
                                                   const int* __restrict__ dst,
                                                   int E, int n, int* bucketTotal) {
    __shared__ int hist[NBUCK];
    int t = threadIdx.x;
    hist[t] = 0;
    __syncthreads();
    int lo = blockIdx.x * EPB;
    int hi = min(lo + EPB, E + n);
    for (int e = lo + t; e < hi; e += NB_T) {
        int d = (e < E) ? dst[e] : (e - E);   // tail = self-loops
        atomicAdd(&hist[d >> BSHIFT], 1);
    }
    __syncthreads();
    int h = hist[t];
    if (h) atomicAdd(&bucketTotal[t], h);
}

// ---- scan 256 bucket totals -> bucketBase[257], cursor copy ----
__global__ void k_bscan(const int* __restrict__ bucketTotal, int* bucketBase,
                        int* bucketCursor, int* rowStart, int E, int n) {
    __shared__ int sh[NBUCK];
    int t = threadIdx.x;
    int v = bucketTotal[t];
    sh[t] = v; __syncthreads();
    for (int off = 1; off < NBUCK; off <<= 1) {
        int u = (t >= off) ? sh[t - off] : 0;
        __syncthreads();
        sh[t] += u;
        __syncthreads();
    }
    int ex = sh[t] - v;          // exclusive
    bucketBase[t] = ex;
    bucketCursor[t] = ex;
    if (t == NBUCK - 1) { bucketBase[NBUCK] = sh[t]; rowStart[n] = E + n; }
}

// ---- Pass A1: scatter packed edges into per-(block,bucket) contiguous runs ----
__global__ __launch_bounds__(NB_T) void k_binScatter(const int* __restrict__ src,
                                                     const int* __restrict__ dst,
                                                     int E, int n, int* bucketCursor,
                                                     unsigned int* __restrict__ binned) {
    __shared__ int hist[NBUCK];
    __shared__ int base[NBUCK];
    int t = threadIdx.x;
    hist[t] = 0;
    __syncthreads();
    int lo = blockIdx.x * EPB;
    int hi = min(lo + EPB, E + n);
    for (int e = lo + t; e < hi; e += NB_T) {
        int d = (e < E) ? dst[e] : (e - E);
        atomicAdd(&hist[d >> BSHIFT], 1);
    }
    __syncthreads();
    int h = hist[t];                 // thread t owns slot t only: no race
    if (h) base[t] = atomicAdd(&bucketCursor[t], h);
    hist[t] = 0;                     // reuse as per-block run cursor
    __syncthreads();
    for (int e = lo + t; e < hi; e += NB_T) {
        int s, d;
        if (e < E) { s = src[e]; d = dst[e]; }
        else       { s = d = e - E; }
        int b = d >> BSHIFT;
        int pos = base[b] + atomicAdd(&hist[b], 1);
        binned[pos] = ((unsigned)(d & 511) << 17) | (unsigned)s;  // N < 2^17
    }
}

// ---- Pass B: per-bucket CSR finalize (count, scan, rowStart/dinv, scatter) ----
__global__ __launch_bounds__(NB_T) void k_csr(const unsigned int* __restrict__ binned,
                                              const int* __restrict__ bucketBase,
                                              int* __restrict__ rowStart,
                                              float* __restrict__ dinv,
                                              int* __restrict__ sortedSrc, int n) {
    __shared__ int cnt[512];
    __shared__ int start[512];
    __shared__ int sh[NB_T];
    int b = blockIdx.x, t = threadIdx.x;
    int ebase = bucketBase[b], eend = bucketBase[b + 1];
    cnt[t] = 0; cnt[t + 256] = 0;
    __syncthreads();
    for (int e = ebase + t; e < eend; e += NB_T)
        atomicAdd(&cnt[binned[e] >> 17], 1);
    __syncthreads();
    // exclusive scan of cnt[0..512), 2 elems/thread
    int c0 = cnt[t * 2], c1 = cnt[t * 2 + 1];
    int ts = c0 + c1;
    sh[t] = ts; __syncthreads();
    for (int off = 1; off < NB_T; off <<= 1) {
        int u = (t >= off) ? sh[t - off] : 0;
        __syncthreads();
        sh[t] += u;
        __syncthreads();
    }
    int pref = sh[t] - ts;
    start[t * 2]     = pref;
    start[t * 2 + 1] = pref + c0;
    __syncthreads();
    // rowStart + dinv (deg incl. self-loop, always > 0)
    int node0 = b << BSHIFT;
    for (int i = t; i < 512; i += NB_T) {
        int node = node0 + i;
        if (node < n) {
            rowStart[node] = ebase + start[i];
            dinv[node] = rsqrtf((float)cnt[i]);
        }
    }
    __syncthreads();
    cnt[t] = 0; cnt[t + 256] = 0;    // reuse as scatter cursor
    __syncthreads();
    for (int e = ebase + t; e < eend; e += NB_T) {
        unsigned p = binned[e];
        int i = p >> 17;
        int pos = ebase + start[i] + atomicAdd(&cnt[i], 1);
        sortedSrc[pos] = (int)(p & 0x1FFFF);
    }
}

// ---- cvt: xh[r][:] = bf16(dinv[r] * x[r][:]), 4 elems/thread ----
__global__ __launch_bounds__(NB_T) void k_cvt(const float* __restrict__ x,
                                              const float* __restrict__ dinv,
                                              unsigned short* __restrict__ xh, int n) {
    int i = blockIdx.x * NB_T + threadIdx.x;      // float4 index
    if (i >= n * 32) return;
    float w = dinv[i >> 5];
    float4 v = *(const float4*)(x + (size_t)i * 4);
    ushort4 o;
    o.x = f2bf(v.x * w); o.y = f2bf(v.y * w);
    o.z = f2bf(v.z * w); o.w = f2bf(v.w * w);
    *(ushort4*)(xh + (size_t)i * 4) = o;
}

// ---- aggregation: G[d] = dinv[d] * sum_{e in row d} Fs[src_e]  (Fs pre-scaled bf16) ----
// one wave per node; lane holds feats 2*lane, 2*lane+1 (ushort2 = 4B gather)
__global__ __launch_bounds__(256) void k_agg(const unsigned short* __restrict__ F,
                                             float* __restrict__ G,
                                             const int* __restrict__ rowStart,
                                             const int* __restrict__ sortedSrc,
                                             const float* __restrict__ dinv, int n) {
    int wave = threadIdx.x >> 6;
    int lane = threadIdx.x & 63;
    int node = blockIdx.x * 4 + wave;
    if (node >= n) return;
    int r0 = rowStart[node], r1 = rowStart[node + 1];
    int f = lane * 2;
    float ax = 0.f, ay = 0.f;
    int e = r0;
    for (; e + 4 <= r1; e += 4) {
        int s0 = sortedSrc[e];
        int s1 = sortedSrc[e + 1];
        int s2 = sortedSrc[e + 2];
        int s3 = sortedSrc[e + 3];
        ushort2 v0 = *(const ushort2*)(F + (size_t)s0 * 128 + f);
        ushort2 v1 = *(const ushort2*)(F + (size_t)s1 * 128 + f);
        ushort2 v2 = *(const ushort2*)(F + (size_t)s2 * 128 + f);
        ushort2 v3 = *(const ushort2*)(F + (size_t)s3 * 128 + f);
        ax += bf2f(v0.x) + bf2f(v1.x) + bf2f(v2.x) + bf2f(v3.x);
        ay += bf2f(v0.y) + bf2f(v1.y) + bf2f(v2.y) + bf2f(v3.y);
    }
    for (; e < r1; e++) {
        int s0 = sortedSrc[e];
        ushort2 v0 = *(const ushort2*)(F + (size_t)s0 * 128 + f);
        ax += bf2f(v0.x); ay += bf2f(v0.y);
    }
    float wd = dinv[node];
    float2 o; o.x = ax * wd; o.y = ay * wd;
    *(float2*)(G + (size_t)node * 128 + f) = o;
}

// ---- f32 GEMM: relu(F@W + b); BF16OUT: write bf16 scaled by dinv[row] ----
__device__ __forceinline__ float f4c(const float4 v, int k) {
    return k == 0 ? v.x : k == 1 ? v.y : k == 2 ? v.z : v.w;
}

template <bool BF16OUT>
__global__ __launch_bounds__(256, 4) void k_gemm(const float* __restrict__ F,
                                                 const float* __restrict__ W,
                                                 const float* __restrict__ bias,
                                                 void* __restrict__ Gout,
                                                 const float* __restrict__ dinv, int n) {
    __shared__ float x_lds[64 * 132];
    int t = threadIdx.x;
    int tileBase = blockIdx.x * 64;

    #pragma unroll
    for (int i = 0; i < 8; i++) {
        int row = i * 8 + (t >> 5);
        int k4  = t & 31;
        int grow = tileBase + row;
        float4 v = make_float4(0.f, 0.f, 0.f, 0.f);
        if (grow < n) v = *(const float4*)&F[(size_t)grow * 128 + k4 * 4];
        *(float4*)&x_lds[row * 132 + k4 * 4] = v;
    }
    __syncthreads();

    int r0 = (t >> 4) * 4;
    int c0 = (t & 15) * 4;
    float acc[4][8];
    #pragma unroll
    for (int i = 0; i < 4; i++)
        #pragma unroll
        for (int j = 0; j < 8; j++) acc[i][j] = 0.f;

    for (int k0 = 0; k0 < 128; k0 += 4) {
        float4 xv[4];
        #pragma unroll
        for (int i = 0; i < 4; i++) xv[i] = *(float4*)&x_lds[(r0 + i) * 132 + k0];
        #pragma unroll
        for (int kk = 0; kk < 4; kk++) {
            float4 w1 = *(const float4*)&W[(k0 + kk) * 128 + c0];
            float4 w2 = *(const float4*)&W[(k0 + kk) * 128 + c0 + 64];
            #pragma unroll
            for (int i = 0; i < 4; i++) {
                float xs = f4c(xv[i], kk);
                acc[i][0] += xs * w1.x; acc[i][1] += xs * w1.y;
                acc[i][2] += xs * w1.z; acc[i][3] += xs * w1.w;
                acc[i][4] += xs * w2.x; acc[i][5] += xs * w2.y;
                acc[i][6] += xs * w2.z; acc[i][7] += xs * w2.w;
            }
        }
    }

    float bv[8];
    #pragma unroll
    for (int j = 0; j < 4; j++) { bv[j] = bias[c0 + j]; bv[4 + j] = bias[c0 + 64 + j]; }
    #pragma unroll
    for (int i = 0; i < 4; i++) {
        int grow = tileBase + r0 + i;
        if (grow < n) {
            float r[8];
            #pragma unroll
            for (int j = 0; j < 8; j++) r[j] = fmaxf(acc[i][j] + bv[j], 0.f);
            if (BF16OUT) {
                float w = dinv[grow];
                ushort4 o1, o2;
                o1.x = f2bf(r[0] * w); o1.y = f2bf(r[1] * w);
                o1.z = f2bf(r[2] * w); o1.w = f2bf(r[3] * w);
                o2.x = f2bf(r[4] * w); o2.y = f2bf(r[5] * w);
                o2.z = f2bf(r[6] * w); o2.w = f2bf(r[7] * w);
                unsigned short* G = (unsigned short*)Gout;
                *(ushort4*)&G[(size_t)grow * 128 + c0]      = o1;
                *(ushort4*)&G[(size_t)grow * 128 + c0 + 64] = o2;
            } else {
                float* G = (float*)Gout;
                *(float4*)&G[(size_t)grow * 128 + c0]      = make_float4(r[0], r[1], r[2], r[3]);
                *(float4*)&G[(size_t)grow * 128 + c0 + 64] = make_float4(r[4], r[5], r[6], r[7]);
            }
        }
    }
}

// ---- final linear 128 -> 2, one wave per node, shuffle reduce ----
__global__ __launch_bounds__(256) void k_out(const float* __restrict__ F,
                                             const float* __restrict__ Wl,
                                             const float* __restrict__ bl,
                                             float* __restrict__ out, int n) {
    int wave = threadIdx.x >> 6;
    int lane = threadIdx.x & 63;
    int node = blockIdx.x * 4 + wave;
    if (node >= n) return;
    int f = lane * 2;
    float2 v = *(const float2*)(F + (size_t)node * 128 + f);
    float w00 = Wl[f * 2 + 0], w01 = Wl[f * 2 + 1];
    float w10 = Wl[f * 2 + 2], w11 = Wl[f * 2 + 3];
    float a0 = v.x * w00 + v.y * w10;
    float a1 = v.x * w01 + v.y * w11;
    for (int m = 32; m >= 1; m >>= 1) {
        a0 += __shfl_xor(a0, m, 64);
        a1 += __shfl_xor(a1, m, 64);
    }
    if (lane == 0) {
        out[(size_t)node * 2 + 0] = a0 + bl[0];
        out[(size_t)node * 2 + 1] = a1 + bl[1];
    }
}

extern "C" void kernel_launch(void* const* d_in, const int* in_sizes, int n_in,
                              void* d_out, int out_size, void* d_ws, size_t ws_size,
                              hipStream_t stream) {
    const float* x   = (const float*)d_in[0];
    const int*   ei  = (const int*)d_in[1];     // int32 (JAX x64 off)
    const float* W1  = (const float*)d_in[2];
    const float* b1  = (const float*)d_in[3];
    const float* W2  = (const float*)d_in[4];
    const float* b2  = (const float*)d_in[5];
    const float* Wl  = (const float*)d_in[6];
    const float* bl  = (const float*)d_in[7];
    float*       out = (float*)d_out;

    const int N = in_sizes[0] / 128;
    const int E = in_sizes[1] / 2;
    const int* src = ei;
    const int* dst = ei + E;

    char* p = (char*)d_ws;
    auto alloc = [&](size_t bytes) -> char* {
        char* r = p;
        p += (bytes + 511) & ~(size_t)511;
        return r;
    };
    float* dinv         = (float*)alloc((size_t)N * 4);
    int*   rowStart     = (int*)alloc((size_t)(N + 1) * 4);
    int*   bucketTotal  = (int*)alloc(NBUCK * 4);
    int*   bucketBase   = (int*)alloc((NBUCK + 1) * 4);
    int*   bucketCursor = (int*)alloc(NBUCK * 4);
    int*   sortedSrc    = (int*)alloc((size_t)(E + N) * 4);
    float* A            = (float*)alloc((size_t)N * 128 * 4);
    float* B            = (float*)alloc((size_t)N * 128 * 4);
    unsigned int*   binned = (unsigned int*)A;    // dead before agg1 writes A
    unsigned short* xh     = (unsigned short*)B;  // dead before gemm2 writes B
    //   timeline: cvt->xh; agg1(xh)->A; gemm1(A)->xh(bf16, as Bh);
    //             agg2(xh)->A; gemm2(A)->B(f32, overwrites); out(B)

    int nbBin  = (E + N + EPB - 1) / EPB;
    int nBuckA = (N + 511) >> BSHIFT;

    k_zero_buckets<<<1, NBUCK, 0, stream>>>(bucketTotal);
    k_binCount<<<nbBin, NB_T, 0, stream>>>(src, dst, E, N, bucketTotal);
    k_bscan<<<1, NBUCK, 0, stream>>>(bucketTotal, bucketBase, bucketCursor, rowStart, E, N);
    k_binScatter<<<nbBin, NB_T, 0, stream>>>(src, dst, E, N, bucketCursor, binned);
    k_csr<<<nBuckA, NB_T, 0, stream>>>(binned, bucketBase, rowStart, dinv, sortedSrc, N);

    // conv1
    k_cvt<<<(N * 32 + NB_T - 1) / NB_T, NB_T, 0, stream>>>(x, dinv, xh, N);
    k_agg<<<(N + 3) / 4, NB_T, 0, stream>>>(xh, A, rowStart, sortedSrc, dinv, N);
    k_gemm<true><<<(N + 63) / 64, NB_T, 0, stream>>>(A, W1, b1, (void*)xh, dinv, N);
    // conv2
    k_agg<<<(N + 3) / 4, NB_T, 0, stream>>>(xh, A, rowStart, sortedSrc, dinv, N);
    k_gemm<false><<<(N + 63) / 64, NB_T, 0, stream>>>(A, W2, b2, (void*)B, dinv, N);
    // final linear
    k_out<<<(N + 3) / 4, NB_T, 0, stream>>>(B, Wl, bl, out, N);
}

// Round 14
// 584.630 us; speedup vs baseline: 1.8877x; 1.0680x over previous
//
#include <hip/hip_runtime.h>
#include <hip/hip_bf16.h>

// GCN 2-layer on MI355X.
// Pipeline (agg-first form, valid since aggregation is linear):
//   xh = bf16(dinv.*x); A = bf16(agg(xh)); Bh = bf16(dinv.*relu(A@W1+b1));
//   A = bf16(agg(Bh)); B = relu(A@W2+b2); out = B@Wl+bl
//
// R6:  k_agg 230us x2, FETCH 800MB (f32 gathers) -> gather-traffic-bound.
// R12: bf16 pre-scaled gathers: k_agg 124us, FETCH 364MB, total 624us,
//      absmax 2.4e-4 (bf16 noise washes out through 128-wide sums). VALU 39%.
// R13 (resubmitted R14 — acquisition timeout):
//      (a) k_agg half-wave: lanes 0-31 edge e, 32-63 edge e+1, uint2 (4 bf16)
//          per lane -> load insts/edge halved; packed unpack; shfl_xor(32)
//          combine; agg OUTPUT now bf16 (halves agg writes + gemm A-reads).
//      (b) k_gemm stages bf16 A -> f32 LDS (inner loop unchanged).

#define NB_T   256
#define NBUCK  256
#define BSHIFT 9
#define EPB    4096   // edges per block in binning passes

__device__ __forceinline__ unsigned short f2bf(float f) {
    unsigned u = __float_as_uint(f);
    u += 0x7FFF + ((u >> 16) & 1);      // round-to-nearest-even
    return (unsigned short)(u >> 16);
}
__device__ __forceinline__ float bflo(unsigned u) {   // low bf16 of a uint
    return __uint_as_float(u << 16);
}
__device__ __forceinline__ float bfhi(unsigned u) {   // high bf16 of a uint
    return __uint_as_float(u & 0xffff0000u);
}

__global__ void k_zero_buckets(int* bucketTotal) {
    bucketTotal[threadIdx.x] = 0;
}

// ---- Pass A0: count edges per bucket (LDS histogram -> global merge) ----
__global__ __launch_bounds__(NB_T) void k_binCount(const int* __restrict__ src,
                                                   const int* __restrict__ dst,
                                                   int E, int n, int* bucketTotal) {
    __shared__ int hist[NBUCK];
    int t = threadIdx.x;
    hist[t] = 0;
    __syncthreads();
    int lo = blockIdx.x * EPB;
    int hi = min(lo + EPB, E + n);
    for (int e = lo + t; e < hi; e += NB_T) {
        int d = (e < E) ? dst[e] : (e - E);   // tail = self-loops
        atomicAdd(&hist[d >> BSHIFT], 1);
    }
    __syncthreads();
    int h = hist[t];
    if (h) atomicAdd(&bucketTotal[t], h);
}

// ---- scan 256 bucket totals -> bucketBase[257], cursor copy ----
__global__ void k_bscan(const int* __restrict__ bucketTotal, int* bucketBase,
                        int* bucketCursor, int* rowStart, int E, int n) {
    __shared__ int sh[NBUCK];
    int t = threadIdx.x;
    int v = bucketTotal[t];
    sh[t] = v; __syncthreads();
    for (int off = 1; off < NBUCK; off <<= 1) {
        int u = (t >= off) ? sh[t - off] : 0;
        __syncthreads();
        sh[t] += u;
        __syncthreads();
    }
    int ex = sh[t] - v;          // exclusive
    bucketBase[t] = ex;
    bucketCursor[t] = ex;
    if (t == NBUCK - 1) { bucketBase[NBUCK] = sh[t]; rowStart[n] = E + n; }
}

// ---- Pass A1: scatter packed edges into per-(block,bucket) contiguous runs ----
__global__ __launch_bounds__(NB_T) void k_binScatter(const int* __restrict__ src,
                                                     const int* __restrict__ dst,
                                                     int E, int n, int* bucketCursor,
                                                     unsigned int* __restrict__ binned) {
    __shared__ int hist[NBUCK];
    __shared__ int base[NBUCK];
    int t = threadIdx.x;
    hist[t] = 0;
    __syncthreads();
    int lo = blockIdx.x * EPB;
    int hi = min(lo + EPB, E + n);
    for (int e = lo + t; e < hi; e += NB_T) {
        int d = (e < E) ? dst[e] : (e - E);
        atomicAdd(&hist[d >> BSHIFT], 1);
    }
    __syncthreads();
    int h = hist[t];                 // thread t owns slot t only: no race
    if (h) base[t] = atomicAdd(&bucketCursor[t], h);
    hist[t] = 0;                     // reuse as per-block run cursor
    __syncthreads();
    for (int e = lo + t; e < hi; e += NB_T) {
        int s, d;
        if (e < E) { s = src[e]; d = dst[e]; }
        else       { s = d = e - E; }
        int b = d >> BSHIFT;
        int pos = base[b] + atomicAdd(&hist[b], 1);
        binned[pos] = ((unsigned)(d & 511) << 17) | (unsigned)s;  // N < 2^17
    }
}

// ---- Pass B: per-bucket CSR finalize (count, scan, rowStart/dinv, scatter) ----
__global__ __launch_bounds__(NB_T) void k_csr(const unsigned int* __restrict__ binned,
                                              const int* __restrict__ bucketBase,
                                              int* __restrict__ rowStart,
                                              float* __restrict__ dinv,
                                              int* __restrict__ sortedSrc, int n) {
    __shared__ int cnt[512];
    __shared__ int start[512];
    __shared__ int sh[NB_T];
    int b = blockIdx.x, t = threadIdx.x;
    int ebase = bucketBase[b], eend = bucketBase[b + 1];
    cnt[t] = 0; cnt[t + 256] = 0;
    __syncthreads();
    for (int e = ebase + t; e < eend; e += NB_T)
        atomicAdd(&cnt[binned[e] >> 17], 1);
    __syncthreads();
    // exclusive scan of cnt[0..512), 2 elems/thread
    int c0 = cnt[t * 2], c1 = cnt[t * 2 + 1];
    int ts = c0 + c1;
    sh[t] = ts; __syncthreads();
    for (int off = 1; off < NB_T; off <<= 1) {
        int u = (t >= off) ? sh[t - off] : 0;
        __syncthreads();
        sh[t] += u;
        __syncthreads();
    }
    int pref = sh[t] - ts;
    start[t * 2]     = pref;
    start[t * 2 + 1] = pref + c0;
    __syncthreads();
    // rowStart + dinv (deg incl. self-loop, always > 0)
    int node0 = b << BSHIFT;
    for (int i = t; i < 512; i += NB_T) {
        int node = node0 + i;
        if (node < n) {
            rowStart[node] = ebase + start[i];
            dinv[node] = rsqrtf((float)cnt[i]);
        }
    }
    __syncthreads();
    cnt[t] = 0; cnt[t + 256] = 0;    // reuse as scatter cursor
    __syncthreads();
    for (int e = ebase + t; e < eend; e += NB_T) {
        unsigned p = binned[e];
        int i = p >> 17;
        int pos = ebase + start[i] + atomicAdd(&cnt[i], 1);
        sortedSrc[pos] = (int)(p & 0x1FFFF);
    }
}

// ---- cvt: xh[r][:] = bf16(dinv[r] * x[r][:]), 4 elems/thread ----
__global__ __launch_bounds__(NB_T) void k_cvt(const float* __restrict__ x,
                                              const float* __restrict__ dinv,
                                              unsigned short* __restrict__ xh, int n) {
    int i = blockIdx.x * NB_T + threadIdx.x;      // float4 index
    if (i >= n * 32) return;
    float w = dinv[i >> 5];
    float4 v = *(const float4*)(x + (size_t)i * 4);
    ushort4 o;
    o.x = f2bf(v.x * w); o.y = f2bf(v.y * w);
    o.z = f2bf(v.z * w); o.w = f2bf(v.w * w);
    *(ushort4*)(xh + (size_t)i * 4) = o;
}

// ---- aggregation: G[d] = bf16( dinv[d] * sum_{e in row d} Fs[src_e] ) ----
// half-wave scheme: lanes 0-31 process even edge, 32-63 odd edge; each lane
// holds feats 4c..4c+3 (uint2 = 4 bf16 = 8B gather). shfl_xor(32) combine.
__global__ __launch_bounds__(256) void k_agg(const unsigned short* __restrict__ F,
                                             unsigned short* __restrict__ G,
                                             const int* __restrict__ rowStart,
                                             const int* __restrict__ sortedSrc,
                                             const float* __restrict__ dinv, int n) {
    int wave = threadIdx.x >> 6;
    int lane = threadIdx.x & 63;
    int node = blockIdx.x * 4 + wave;
    if (node >= n) return;
    int r0 = rowStart[node], r1 = rowStart[node + 1];
    int half = lane >> 5;            // 0: even edge, 1: odd edge
    int c    = lane & 31;            // feat group (4 feats)
    size_t fo = (size_t)(c * 4);
    float a0 = 0.f, a1 = 0.f, a2 = 0.f, a3 = 0.f;
    int e = r0;
    for (; e + 8 <= r1; e += 8) {    // 4 gathers in flight
        int s0 = sortedSrc[e     + half];
        int s1 = sortedSrc[e + 2 + half];
        int s2 = sortedSrc[e + 4 + half];
        int s3 = sortedSrc[e + 6 + half];
        uint2 v0 = *(const uint2*)(F + (size_t)s0 * 128 + fo);
        uint2 v1 = *(const uint2*)(F + (size_t)s1 * 128 + fo);
        uint2 v2 = *(const uint2*)(F + (size_t)s2 * 128 + fo);
        uint2 v3 = *(const uint2*)(F + (size_t)s3 * 128 + fo);
        a0 += bflo(v0.x) + bflo(v1.x) + bflo(v2.x) + bflo(v3.x);
        a1 += bfhi(v0.x) + bfhi(v1.x) + bfhi(v2.x) + bfhi(v3.x);
        a2 += bflo(v0.y) + bflo(v1.y) + bflo(v2.y) + bflo(v3.y);
        a3 += bfhi(v0.y) + bfhi(v1.y) + bfhi(v2.y) + bfhi(v3.y);
    }
    for (; e + 2 <= r1; e += 2) {
        int s0 = sortedSrc[e + half];
        uint2 v0 = *(const uint2*)(F + (size_t)s0 * 128 + fo);
        a0 += bflo(v0.x); a1 += bfhi(v0.x);
        a2 += bflo(v0.y); a3 += bfhi(v0.y);
    }
    if (e < r1 && half == 0) {       // odd tail edge: lanes 0-31 only
        int s0 = sortedSrc[e];
        uint2 v0 = *(const uint2*)(F + (size_t)s0 * 128 + fo);
        a0 += bflo(v0.x); a1 += bfhi(v0.x);
        a2 += bflo(v0.y); a3 += bfhi(v0.y);
    }
    a0 += __shfl_xor(a0, 32, 64);
    a1 += __shfl_xor(a1, 32, 64);
    a2 += __shfl_xor(a2, 32, 64);
    a3 += __shfl_xor(a3, 32, 64);
    if (half == 0) {
        float wd = dinv[node];
        ushort4 o;
        o.x = f2bf(a0 * wd); o.y = f2bf(a1 * wd);
        o.z = f2bf(a2 * wd); o.w = f2bf(a3 * wd);
        *(ushort4*)(G + (size_t)node * 128 + fo) = o;
    }
}

// ---- f32 GEMM (bf16 input A): relu(F@W + b); BF16OUT: bf16 scaled by dinv ----
__device__ __forceinline__ float f4c(const float4 v, int k) {
    return k == 0 ? v.x : k == 1 ? v.y : k == 2 ? v.z : v.w;
}

template <bool BF16OUT>
__global__ __launch_bounds__(256, 4) void k_gemm(const unsigned short* __restrict__ F,
                                                 const float* __restrict__ W,
                                                 const float* __restrict__ bias,
                                                 void* __restrict__ Gout,
                                                 const float* __restrict__ dinv, int n) {
    __shared__ float x_lds[64 * 132];
    int t = threadIdx.x;
    int tileBase = blockIdx.x * 64;

    // stage bf16 tile -> f32 LDS (padded stride 132). 64x128 bf16 = 1024 uint4.
    #pragma unroll
    for (int i = 0; i < 4; i++) {
        int idx = i * 256 + t;           // uint4 index (8 bf16)
        int row = idx >> 4;
        int c8  = (idx & 15) * 8;
        int grow = tileBase + row;
        uint4 v = make_uint4(0, 0, 0, 0);
        if (grow < n) v = *(const uint4*)(F + (size_t)grow * 128 + c8);
        float* dst = &x_lds[row * 132 + c8];
        dst[0] = bflo(v.x); dst[1] = bfhi(v.x);
        dst[2] = bflo(v.y); dst[3] = bfhi(v.y);
        dst[4] = bflo(v.z); dst[5] = bfhi(v.z);
        dst[6] = bflo(v.w); dst[7] = bfhi(v.w);
    }
    __syncthreads();

    int r0 = (t >> 4) * 4;
    int c0 = (t & 15) * 4;
    float acc[4][8];
    #pragma unroll
    for (int i = 0; i < 4; i++)
        #pragma unroll
        for (int j = 0; j < 8; j++) acc[i][j] = 0.f;

    for (int k0 = 0; k0 < 128; k0 += 4) {
        float4 xv[4];
        #pragma unroll
        for (int i = 0; i < 4; i++) xv[i] = *(float4*)&x_lds[(r0 + i) * 132 + k0];
        #pragma unroll
        for (int kk = 0; kk < 4; kk++) {
            float4 w1 = *(const float4*)&W[(k0 + kk) * 128 + c0];
            float4 w2 = *(const float4*)&W[(k0 + kk) * 128 + c0 + 64];
            #pragma unroll
            for (int i = 0; i < 4; i++) {
                float xs = f4c(xv[i], kk);
                acc[i][0] += xs * w1.x; acc[i][1] += xs * w1.y;
                acc[i][2] += xs * w1.z; acc[i][3] += xs * w1.w;
                acc[i][4] += xs * w2.x; acc[i][5] += xs * w2.y;
                acc[i][6] += xs * w2.z; acc[i][7] += xs * w2.w;
            }
        }
    }

    float bv[8];
    #pragma unroll
    for (int j = 0; j < 4; j++) { bv[j] = bias[c0 + j]; bv[4 + j] = bias[c0 + 64 + j]; }
    #pragma unroll
    for (int i = 0; i < 4; i++) {
        int grow = tileBase + r0 + i;
        if (grow < n) {
            float r[8];
            #pragma unroll
            for (int j = 0; j < 8; j++) r[j] = fmaxf(acc[i][j] + bv[j], 0.f);
            if (BF16OUT) {
                float w = dinv[grow];
                ushort4 o1, o2;
                o1.x = f2bf(r[0] * w); o1.y = f2bf(r[1] * w);
                o1.z = f2bf(r[2] * w); o1.w = f2bf(r[3] * w);
                o2.x = f2bf(r[4] * w); o2.y = f2bf(r[5] * w);
                o2.z = f2bf(r[6] * w); o2.w = f2bf(r[7] * w);
                unsigned short* G = (unsigned short*)Gout;
                *(ushort4*)&G[(size_t)grow * 128 + c0]      = o1;
                *(ushort4*)&G[(size_t)grow * 128 + c0 + 64] = o2;
            } else {
                float* G = (float*)Gout;
                *(float4*)&G[(size_t)grow * 128 + c0]      = make_float4(r[0], r[1], r[2], r[3]);
                *(float4*)&G[(size_t)grow * 128 + c0 + 64] = make_float4(r[4], r[5], r[6], r[7]);
            }
        }
    }
}

// ---- final linear 128 -> 2, one wave per node, shuffle reduce ----
__global__ __launch_bounds__(256) void k_out(const float* __restrict__ F,
                                             const float* __restrict__ Wl,
                                             const float* __restrict__ bl,
                                             float* __restrict__ out, int n) {
    int wave = threadIdx.x >> 6;
    int lane = threadIdx.x & 63;
    int node = blockIdx.x * 4 + wave;
    if (node >= n) return;
    int f = lane * 2;
    float2 v = *(const float2*)(F + (size_t)node * 128 + f);
    float w00 = Wl[f * 2 + 0], w01 = Wl[f * 2 + 1];
    float w10 = Wl[f * 2 + 2], w11 = Wl[f * 2 + 3];
    float a0 = v.x * w00 + v.y * w10;
    float a1 = v.x * w01 + v.y * w11;
    for (int m = 32; m >= 1; m >>= 1) {
        a0 += __shfl_xor(a0, m, 64);
        a1 += __shfl_xor(a1, m, 64);
    }
    if (lane == 0) {
        out[(size_t)node * 2 + 0] = a0 + bl[0];
        out[(size_t)node * 2 + 1] = a1 + bl[1];
    }
}

extern "C" void kernel_launch(void* const* d_in, const int* in_sizes, int n_in,
                              void* d_out, int out_size, void* d_ws, size_t ws_size,
                              hipStream_t stream) {
    const float* x   = (const float*)d_in[0];
    const int*   ei  = (const int*)d_in[1];     // int32 (JAX x64 off)
    const float* W1  = (const float*)d_in[2];
    const float* b1  = (const float*)d_in[3];
    const float* W2  = (const float*)d_in[4];
    const float* b2  = (const float*)d_in[5];
    const float* Wl  = (const float*)d_in[6];
    const float* bl  = (const float*)d_in[7];
    float*       out = (float*)d_out;

    const int N = in_sizes[0] / 128;
    const int E = in_sizes[1] / 2;
    const int* src = ei;
    const int* dst = ei + E;

    char* p = (char*)d_ws;
    auto alloc = [&](size_t bytes) -> char* {
        char* r = p;
        p += (bytes + 511) & ~(size_t)511;
        return r;
    };
    float* dinv         = (float*)alloc((size_t)N * 4);
    int*   rowStart     = (int*)alloc((size_t)(N + 1) * 4);
    int*   bucketTotal  = (int*)alloc(NBUCK * 4);
    int*   bucketBase   = (int*)alloc((NBUCK + 1) * 4);
    int*   bucketCursor = (int*)alloc(NBUCK * 4);
    int*   sortedSrc    = (int*)alloc((size_t)(E + N) * 4);
    float* A            = (float*)alloc((size_t)N * 128 * 4);
    float* B            = (float*)alloc((size_t)N * 128 * 4);
    unsigned int*   binned = (unsigned int*)A;    // dead before agg1 writes A
    unsigned short* Abf    = (unsigned short*)A;  // bf16 agg output
    unsigned short* xh     = (unsigned short*)B;  // dead before gemm2 writes B
    //   timeline: cvt->xh(B); agg1(xh)->Abf(A); gemm1(Abf)->xh(B, as Bh);
    //             agg2(xh)->Abf(A); gemm2(Abf)->B(f32, overwrites); out(B)

    int nbBin  = (E + N + EPB - 1) / EPB;
    int nBuckA = (N + 511) >> BSHIFT;

    k_zero_buckets<<<1, NBUCK, 0, stream>>>(bucketTotal);
    k_binCount<<<nbBin, NB_T, 0, stream>>>(src, dst, E, N, bucketTotal);
    k_bscan<<<1, NBUCK, 0, stream>>>(bucketTotal, bucketBase, bucketCursor, rowStart, E, N);
    k_binScatter<<<nbBin, NB_T, 0, stream>>>(src, dst, E, N, bucketCursor, binned);
    k_csr<<<nBuckA, NB_T, 0, stream>>>(binned, bucketBase, rowStart, dinv, sortedSrc, N);

    // conv1
    k_cvt<<<(N * 32 + NB_T - 1) / NB_T, NB_T, 0, stream>>>(x, dinv, xh, N);
    k_agg<<<(N + 3) / 4, NB_T, 0, stream>>>(xh, Abf, rowStart, sortedSrc, dinv, N);
    k_gemm<true><<<(N + 63) / 64, NB_T, 0, stream>>>(Abf, W1, b1, (void*)xh, dinv, N);
    // conv2
    k_agg<<<(N + 3) / 4, NB_T, 0, stream>>>(xh, Abf, rowStart, sortedSrc, dinv, N);
    k_gemm<false><<<(N + 63) / 64, NB_T, 0, stream>>>(Abf, W2, b2, (void*)B, dinv, N);
    // final linear
    k_out<<<(N + 3) / 4, NB_T, 0, stream>>>(B, Wl, bl, out, N);
}

// Round 16
// 497.513 us; speedup vs baseline: 2.2183x; 1.1751x over previous
//
#include <hip/hip_runtime.h>
#include <hip/hip_bf16.h>

// GCN 2-layer on MI355X.
// Pipeline (agg-first form, valid since aggregation is linear):
//   xh = bf16(dinv.*x); A = bf16(agg(xh)); Bh = bf16(dinv.*relu(A@W1+b1));
//   A = bf16(agg(Bh)); B = relu(A@W2+b2); out = B@Wl+bl
//
// R6:  k_agg 230us x2, FETCH 800MB (f32 gathers) -> gather-traffic-bound.
// R12: bf16 pre-scaled gathers: k_agg 124us, FETCH 364MB, total 624us.
// R14: half-wave agg + bf16 agg out: k_agg 110us, WRITE 25MB, total 584us,
//      absmax still 2.4e-4. Agg near floor; ~364us below top-5 cutoff.
// R15 (resubmitted R16 — acquisition timeout): MFMA GEMM (both inputs bf16):
//      v_mfma_f32_16x16x32_bf16, 64-row tile, 4 waves x 8 col-tiles x 4
//      k-steps; W pre-transposed to Wt[col][k] bf16 (k_cvtW) staged in LDS
//      (pad 136 -> 2-way banks, free). C/D layout per m89: col=lane&15,
//      row=(lane>>4)*4+reg. A/B frags share one lane->k map (slot symmetry).

#define NB_T   256
#define NBUCK  256
#define BSHIFT 9
#define EPB    4096   // edges per block in binning passes

typedef __attribute__((ext_vector_type(8))) short bf16x8;
typedef __attribute__((ext_vector_type(4))) float f32x4;

__device__ __forceinline__ unsigned short f2bf(float f) {
    unsigned u = __float_as_uint(f);
    u += 0x7FFF + ((u >> 16) & 1);      // round-to-nearest-even
    return (unsigned short)(u >> 16);
}
__device__ __forceinline__ float bflo(unsigned u) {   // low bf16 of a uint
    return __uint_as_float(u << 16);
}
__device__ __forceinline__ float bfhi(unsigned u) {   // high bf16 of a uint
    return __uint_as_float(u & 0xffff0000u);
}

__global__ void k_zero_buckets(int* bucketTotal) {
    bucketTotal[threadIdx.x] = 0;
}

// ---- Pass A0: count edges per bucket (LDS histogram -> global merge) ----
__global__ __launch_bounds__(NB_T) void k_binCount(const int* __restrict__ src,
                                                   const int* __restrict__ dst,
                                                   int E, int n, int* bucketTotal) {
    __shared__ int hist[NBUCK];
    int t = threadIdx.x;
    hist[t] = 0;
    __syncthreads();
    int lo = blockIdx.x * EPB;
    int hi = min(lo + EPB, E + n);
    for (int e = lo + t; e < hi; e += NB_T) {
        int d = (e < E) ? dst[e] : (e - E);   // tail = self-loops
        atomicAdd(&hist[d >> BSHIFT], 1);
    }
    __syncthreads();
    int h = hist[t];
    if (h) atomicAdd(&bucketTotal[t], h);
}

// ---- scan 256 bucket totals -> bucketBase[257], cursor copy ----
__global__ void k_bscan(const int* __restrict__ bucketTotal, int* bucketBase,
                        int* bucketCursor, int* rowStart, int E, int n) {
    __shared__ int sh[NBUCK];
    int t = threadIdx.x;
    int v = bucketTotal[t];
    sh[t] = v; __syncthreads();
    for (int off = 1; off < NBUCK; off <<= 1) {
        int u = (t >= off) ? sh[t - off] : 0;
        __syncthreads();
        sh[t] += u;
        __syncthreads();
    }
    int ex = sh[t] - v;          // exclusive
    bucketBase[t] = ex;
    bucketCursor[t] = ex;
    if (t == NBUCK - 1) { bucketBase[NBUCK] = sh[t]; rowStart[n] = E + n; }
}

// ---- Pass A1: scatter packed edges into per-(block,bucket) contiguous runs ----
__global__ __launch_bounds__(NB_T) void k_binScatter(const int* __restrict__ src,
                                                     const int* __restrict__ dst,
                                                     int E, int n, int* bucketCursor,
                                                     unsigned int* __restrict__ binned) {
    __shared__ int hist[NBUCK];
    __shared__ int base[NBUCK];
    int t = threadIdx.x;
    hist[t] = 0;
    __syncthreads();
    int lo = blockIdx.x * EPB;
    int hi = min(lo + EPB, E + n);
    for (int e = lo + t; e < hi; e += NB_T) {
        int d = (e < E) ? dst[e] : (e - E);
        atomicAdd(&hist[d >> BSHIFT], 1);
    }
    __syncthreads();
    int h = hist[t];                 // thread t owns slot t only: no race
    if (h) base[t] = atomicAdd(&bucketCursor[t], h);
    hist[t] = 0;                     // reuse as per-block run cursor
    __syncthreads();
    for (int e = lo + t; e < hi; e += NB_T) {
        int s, d;
        if (e < E) { s = src[e]; d = dst[e]; }
        else       { s = d = e - E; }
        int b = d >> BSHIFT;
        int pos = base[b] + atomicAdd(&hist[b], 1);
        binned[pos] = ((unsigned)(d & 511) << 17) | (unsigned)s;  // N < 2^17
    }
}

// ---- Pass B: per-bucket CSR finalize (count, scan, rowStart/dinv, scatter) ----
__global__ __launch_bounds__(NB_T) void k_csr(const unsigned int* __restrict__ binned,
                                              const int* __restrict__ bucketBase,
                                              int* __restrict__ rowStart,
                                              float* __restrict__ dinv,
                                              int* __restrict__ sortedSrc, int n) {
    __shared__ int cnt[512];
    __shared__ int start[512];
    __shared__ int sh[NB_T];
    int b = blockIdx.x, t = threadIdx.x;
    int ebase = bucketBase[b], eend = bucketBase[b + 1];
    cnt[t] = 0; cnt[t + 256] = 0;
    __syncthreads();
    for (int e = ebase + t; e < eend; e += NB_T)
        atomicAdd(&cnt[binned[e] >> 17], 1);
    __syncthreads();
    // exclusive scan of cnt[0..512), 2 elems/thread
    int c0 = cnt[t * 2], c1 = cnt[t * 2 + 1];
    int ts = c0 + c1;
    sh[t] = ts; __syncthreads();
    for (int off = 1; off < NB_T; off <<= 1) {
        int u = (t >= off) ? sh[t - off] : 0;
        __syncthreads();
        sh[t] += u;
        __syncthreads();
    }
    int pref = sh[t] - ts;
    start[t * 2]     = pref;
    start[t * 2 + 1] = pref + c0;
    __syncthreads();
    // rowStart + dinv (deg incl. self-loop, always > 0)
    int node0 = b << BSHIFT;
    for (int i = t; i < 512; i += NB_T) {
        int node = node0 + i;
        if (node < n) {
            rowStart[node] = ebase + start[i];
            dinv[node] = rsqrtf((float)cnt[i]);
        }
    }
    __syncthreads();
    cnt[t] = 0; cnt[t + 256] = 0;    // reuse as scatter cursor
    __syncthreads();
    for (int e = ebase + t; e < eend; e += NB_T) {
        unsigned p = binned[e];
        int i = p >> 17;
        int pos = ebase + start[i] + atomicAdd(&cnt[i], 1);
        sortedSrc[pos] = (int)(p & 0x1FFFF);
    }
}

// ---- cvt: xh[r][:] = bf16(dinv[r] * x[r][:]), 4 elems/thread ----
__global__ __launch_bounds__(NB_T) void k_cvt(const float* __restrict__ x,
                                              const float* __restrict__ dinv,
                                              unsigned short* __restrict__ xh, int n) {
    int i = blockIdx.x * NB_T + threadIdx.x;      // float4 index
    if (i >= n * 32) return;
    float w = dinv[i >> 5];
    float4 v = *(const float4*)(x + (size_t)i * 4);
    ushort4 o;
    o.x = f2bf(v.x * w); o.y = f2bf(v.y * w);
    o.z = f2bf(v.z * w); o.w = f2bf(v.w * w);
    *(ushort4*)(xh + (size_t)i * 4) = o;
}

// ---- cvtW: Wt[c][k] = bf16(W[k][c]) -- transposed bf16 weights ----
__global__ __launch_bounds__(NB_T) void k_cvtW(const float* __restrict__ W,
                                               unsigned short* __restrict__ Wt) {
    int i = blockIdx.x * NB_T + threadIdx.x;   // 16384 elems
    int c = i >> 7, k = i & 127;
    Wt[c * 128 + k] = f2bf(W[k * 128 + c]);
}

// ---- aggregation: G[d] = bf16( dinv[d] * sum_{e in row d} Fs[src_e] ) ----
// half-wave scheme: lanes 0-31 process even edge, 32-63 odd edge; each lane
// holds feats 4c..4c+3 (uint2 = 4 bf16 = 8B gather). shfl_xor(32) combine.
__global__ __launch_bounds__(256) void k_agg(const unsigned short* __restrict__ F,
                                             unsigned short* __restrict__ G,
                                             const int* __restrict__ rowStart,
                                             const int* __restrict__ sortedSrc,
                                             const float* __restrict__ dinv, int n) {
    int wave = threadIdx.x >> 6;
    int lane = threadIdx.x & 63;
    int node = blockIdx.x * 4 + wave;
    if (node >= n) return;
    int r0 = rowStart[node], r1 = rowStart[node + 1];
    int half = lane >> 5;            // 0: even edge, 1: odd edge
    int c    = lane & 31;            // feat group (4 feats)
    size_t fo = (size_t)(c * 4);
    float a0 = 0.f, a1 = 0.f, a2 = 0.f, a3 = 0.f;
    int e = r0;
    for (; e + 8 <= r1; e += 8) {    // 4 gathers in flight
        int s0 = sortedSrc[e     + half];
        int s1 = sortedSrc[e + 2 + half];
        int s2 = sortedSrc[e + 4 + half];
        int s3 = sortedSrc[e + 6 + half];
        uint2 v0 = *(const uint2*)(F + (size_t)s0 * 128 + fo);
        uint2 v1 = *(const uint2*)(F + (size_t)s1 * 128 + fo);
        uint2 v2 = *(const uint2*)(F + (size_t)s2 * 128 + fo);
        uint2 v3 = *(const uint2*)(F + (size_t)s3 * 128 + fo);
        a0 += bflo(v0.x) + bflo(v1.x) + bflo(v2.x) + bflo(v3.x);
        a1 += bfhi(v0.x) + bfhi(v1.x) + bfhi(v2.x) + bfhi(v3.x);
        a2 += bflo(v0.y) + bflo(v1.y) + bflo(v2.y) + bflo(v3.y);
        a3 += bfhi(v0.y) + bfhi(v1.y) + bfhi(v2.y) + bfhi(v3.y);
    }
    for (; e + 2 <= r1; e += 2) {
        int s0 = sortedSrc[e + half];
        uint2 v0 = *(const uint2*)(F + (size_t)s0 * 128 + fo);
        a0 += bflo(v0.x); a1 += bfhi(v0.x);
        a2 += bflo(v0.y); a3 += bfhi(v0.y);
    }
    if (e < r1 && half == 0) {       // odd tail edge: lanes 0-31 only
        int s0 = sortedSrc[e];
        uint2 v0 = *(const uint2*)(F + (size_t)s0 * 128 + fo);
        a0 += bflo(v0.x); a1 += bfhi(v0.x);
        a2 += bflo(v0.y); a3 += bfhi(v0.y);
    }
    a0 += __shfl_xor(a0, 32, 64);
    a1 += __shfl_xor(a1, 32, 64);
    a2 += __shfl_xor(a2, 32, 64);
    a3 += __shfl_xor(a3, 32, 64);
    if (half == 0) {
        float wd = dinv[node];
        ushort4 o;
        o.x = f2bf(a0 * wd); o.y = f2bf(a1 * wd);
        o.z = f2bf(a2 * wd); o.w = f2bf(a3 * wd);
        *(ushort4*)(G + (size_t)node * 128 + fo) = o;
    }
}

// ---- MFMA GEMM: G = [bf16(dinv.*)]relu(F@W + b), F bf16, Wt bf16 [col][k] ----
// block = 4 waves x 16 rows = 64 rows; wave: 8 col-tiles of 16, K=128 in 4 steps.
// A frag: lane l -> row (l&15), k = kk*32 + (l>>4)*8 + j (contiguous 16B).
// B frag: lane l -> col (l&15), same k slots, from LDS Wt (pad 136: 2-way banks).
// D frag: col = l&15, row = (l>>4)*4 + r  [m89-verified].
template <bool BF16OUT>
__global__ __launch_bounds__(256, 4) void k_gemm(const unsigned short* __restrict__ F,
                                                 const unsigned short* __restrict__ Wt,
                                                 const float* __restrict__ bias,
                                                 void* __restrict__ Gout,
                                                 const float* __restrict__ dinv, int n) {
    __shared__ unsigned short wlds[128][136];   // 34.8 KB
    int t = threadIdx.x;

    // stage Wt: 128 cols x 128 k bf16 = 2048 uint4, coalesced
    #pragma unroll
    for (int i = 0; i < 8; i++) {
        int idx = i * 256 + t;
        int col = idx >> 4, seg = idx & 15;
        uint4 v = *(const uint4*)(Wt + col * 128 + seg * 8);
        *(uint4*)&wlds[col][seg * 8] = v;
    }
    __syncthreads();

    int wv = t >> 6, l = t & 63;
    int rl = l & 15;                 // A-row / B-col / D-col lane index
    int kg = l >> 4;                 // k-group
    int rowA = blockIdx.x * 64 + wv * 16 + rl;

    // A fragments (4 k-steps), zero-padded past n
    bf16x8 afr[4];
    #pragma unroll
    for (int kk = 0; kk < 4; kk++) {
        if (rowA < n) afr[kk] = *(const bf16x8*)(F + (size_t)rowA * 128 + kk * 32 + kg * 8);
        else          afr[kk] = (bf16x8)(short)0;
    }

    f32x4 acc[8];
    #pragma unroll
    for (int c16 = 0; c16 < 8; c16++) acc[c16] = (f32x4)0.f;

    #pragma unroll
    for (int c16 = 0; c16 < 8; c16++) {
        #pragma unroll
        for (int kk = 0; kk < 4; kk++) {
            bf16x8 bfr = *(const bf16x8*)&wlds[c16 * 16 + rl][kk * 32 + kg * 8];
            acc[c16] = __builtin_amdgcn_mfma_f32_16x16x32_bf16(afr[kk], bfr, acc[c16], 0, 0, 0);
        }
    }

    // epilogue: D row = blockBase + wv*16 + kg*4 + r, col = c16*16 + rl
    int rowBase = blockIdx.x * 64 + wv * 16 + kg * 4;
    #pragma unroll
    for (int r = 0; r < 4; r++) {
        int rowo = rowBase + r;
        if (rowo >= n) continue;
        float w = BF16OUT ? dinv[rowo] : 1.f;
        #pragma unroll
        for (int c16 = 0; c16 < 8; c16++) {
            int col = c16 * 16 + rl;
            float v = fmaxf(acc[c16][r] + bias[col], 0.f);
            if (BF16OUT) {
                ((unsigned short*)Gout)[(size_t)rowo * 128 + col] = f2bf(v * w);
            } else {
                ((float*)Gout)[(size_t)rowo * 128 + col] = v;
            }
        }
    }
}

// ---- final linear 128 -> 2, one wave per node, shuffle reduce ----
__global__ __launch_bounds__(256) void k_out(const float* __restrict__ F,
                                             const float* __restrict__ Wl,
                                             const float* __restrict__ bl,
                                             float* __restrict__ out, int n) {
    int wave = threadIdx.x >> 6;
    int lane = threadIdx.x & 63;
    int node = blockIdx.x * 4 + wave;
    if (node >= n) return;
    int f = lane * 2;
    float2 v = *(const float2*)(F + (size_t)node * 128 + f);
    float w00 = Wl[f * 2 + 0], w01 = Wl[f * 2 + 1];
    float w10 = Wl[f * 2 + 2], w11 = Wl[f * 2 + 3];
    float a0 = v.x * w00 + v.y * w10;
    float a1 = v.x * w01 + v.y * w11;
    for (int m = 32; m >= 1; m >>= 1) {
        a0 += __shfl_xor(a0, m, 64);
        a1 += __shfl_xor(a1, m, 64);
    }
    if (lane == 0) {
        out[(size_t)node * 2 + 0] = a0 + bl[0];
        out[(size_t)node * 2 + 1] = a1 + bl[1];
    }
}

extern "C" void kernel_launch(void* const* d_in, const int* in_sizes, int n_in,
                              void* d_out, int out_size, void* d_ws, size_t ws_size,
                              hipStream_t stream) {
    const float* x   = (const float*)d_in[0];
    const int*   ei  = (const int*)d_in[1];     // int32 (JAX x64 off)
    const float* W1  = (const float*)d_in[2];
    const float* b1  = (const float*)d_in[3];
    const float* W2  = (const float*)d_in[4];
    const float* b2  = (const float*)d_in[5];
    const float* Wl  = (const float*)d_in[6];
    const float* bl  = (const float*)d_in[7];
    float*       out = (float*)d_out;

    const int N = in_sizes[0] / 128;
    const int E = in_sizes[1] / 2;
    const int* src = ei;
    const int* dst = ei + E;

    char* p = (char*)d_ws;
    auto alloc = [&](size_t bytes) -> char* {
        char* r = p;
        p += (bytes + 511) & ~(size_t)511;
        return r;
    };
    float* dinv         = (float*)alloc((size_t)N * 4);
    int*   rowStart     = (int*)alloc((size_t)(N + 1) * 4);
    int*   bucketTotal  = (int*)alloc(NBUCK * 4);
    int*   bucketBase   = (int*)alloc((NBUCK + 1) * 4);
    int*   bucketCursor = (int*)alloc(NBUCK * 4);
    int*   sortedSrc    = (int*)alloc((size_t)(E + N) * 4);
    unsigned short* Wt1 = (unsigned short*)alloc(128 * 128 * 2);
    unsigned short* Wt2 = (unsigned short*)alloc(128 * 128 * 2);
    float* A            = (float*)alloc((size_t)N * 128 * 4);
    float* B            = (float*)alloc((size_t)N * 128 * 4);
    unsigned int*   binned = (unsigned int*)A;    // dead before agg1 writes A
    unsigned short* Abf    = (unsigned short*)A;  // bf16 agg output
    unsigned short* xh     = (unsigned short*)B;  // dead before gemm2 writes B
    //   timeline: cvt->xh(B); agg1(xh)->Abf(A); gemm1(Abf)->xh(B, as Bh);
    //             agg2(xh)->Abf(A); gemm2(Abf)->B(f32, overwrites); out(B)

    int nbBin  = (E + N + EPB - 1) / EPB;
    int nBuckA = (N + 511) >> BSHIFT;

    k_zero_buckets<<<1, NBUCK, 0, stream>>>(bucketTotal);
    k_binCount<<<nbBin, NB_T, 0, stream>>>(src, dst, E, N, bucketTotal);
    k_bscan<<<1, NBUCK, 0, stream>>>(bucketTotal, bucketBase, bucketCursor, rowStart, E, N);
    k_binScatter<<<nbBin, NB_T, 0, stream>>>(src, dst, E, N, bucketCursor, binned);
    k_csr<<<nBuckA, NB_T, 0, stream>>>(binned, bucketBase, rowStart, dinv, sortedSrc, N);
    k_cvtW<<<64, NB_T, 0, stream>>>(W1, Wt1);
    k_cvtW<<<64, NB_T, 0, stream>>>(W2, Wt2);

    // conv1
    k_cvt<<<(N * 32 + NB_T - 1) / NB_T, NB_T, 0, stream>>>(x, dinv, xh, N);
    k_agg<<<(N + 3) / 4, NB_T, 0, stream>>>(xh, Abf, rowStart, sortedSrc, dinv, N);
    k_gemm<true><<<(N + 63) / 64, NB_T, 0, stream>>>(Abf, Wt1, b1, (void*)xh, dinv, N);
    // conv2
    k_agg<<<(N + 3) / 4, NB_T, 0, stream>>>(xh, Abf, rowStart, sortedSrc, dinv, N);
    k_gemm<false><<<(N + 63) / 64, NB_T, 0, stream>>>(Abf, Wt2, b2, (void*)B, dinv, N);
    // final linear
    k_out<<<(N + 3) / 4, NB_T, 0, stream>>>(B, Wl, bl, out, N);
}